// Round 7
// baseline (340.592 us; speedup 1.0000x reference)
//
#include <hip/hip_runtime.h>

#define LOG2E 1.44269504088896340736f

typedef __attribute__((ext_vector_type(4)))  float  f32x4;
typedef __attribute__((ext_vector_type(16))) float  f32x16;
typedef __attribute__((ext_vector_type(8)))  __bf16 bf16x8;
typedef __attribute__((ext_vector_type(4)))  __bf16 bf16x4;

static __device__ __forceinline__ f32x4 mfma16(bf16x8 a, bf16x8 b, f32x4 c) {
  return __builtin_amdgcn_mfma_f32_16x16x32_bf16(a, b, c, 0, 0, 0);
}
static __device__ __forceinline__ f32x16 mfma32(bf16x8 a, bf16x8 b, f32x16 c) {
  return __builtin_amdgcn_mfma_f32_32x32x16_bf16(a, b, c, 0, 0, 0);
}

// B=8, L=4096, C=256, C8=32 hardcoded.

// ---------------- fp32 -> bf16 conversion (vectorized) ----------------
__global__ void cvt_f32_to_bf16(const float* __restrict__ s, __bf16* __restrict__ d, int n4) {
  const int stride = gridDim.x * blockDim.x;
  for (int i = blockIdx.x * blockDim.x + threadIdx.x; i < n4; i += stride) {
    const float4 v = reinterpret_cast<const float4*>(s)[i];
    bf16x4 o = { (__bf16)v.x, (__bf16)v.y, (__bf16)v.z, (__bf16)v.w };
    reinterpret_cast<bf16x4*>(d)[i] = o;
  }
}

// all three weight matrices in one launch
__global__ __launch_bounds__(256) void cvt_weights(
    const float* __restrict__ wq, const float* __restrict__ wk, const float* __restrict__ wv,
    __bf16* __restrict__ dq, __bf16* __restrict__ dk, __bf16* __restrict__ dv) {
  const int i = blockIdx.x * 256 + threadIdx.x;
  const float* s; __bf16* d; int off;
  if (i < 2048)      { s = wq; d = dq; off = i; }
  else if (i < 4096) { s = wk; d = dk; off = i - 2048; }
  else               { s = wv; d = dv; off = i - 4096; }
  const float4 v = reinterpret_cast<const float4*>(s)[off];
  bf16x4 o = { (__bf16)v.x, (__bf16)v.y, (__bf16)v.z, (__bf16)v.w };
  reinterpret_cast<bf16x4*>(d)[off] = o;
}

// ---------------- Q/K projection: split-bf16 out, Q pre-scaled by LOG2E ----------------
__global__ __launch_bounds__(256) void qk_proj(
    const __bf16* __restrict__ x, const __bf16* __restrict__ wq, const __bf16* __restrict__ wk,
    const float* __restrict__ bq, const float* __restrict__ bk,
    __bf16* __restrict__ Qh, __bf16* __restrict__ Ql,
    __bf16* __restrict__ Kh, __bf16* __restrict__ Kl)
{
  const int w = threadIdx.x >> 6, lane = threadIdx.x & 63;
  const int lo = lane & 15, hi = lane >> 4;
  const int m0 = blockIdx.x * 64 + w * 16;
  f32x4 acc[4] = {};
  for (int ks = 0; ks < 8; ++ks) {
    const bf16x8 a = *reinterpret_cast<const bf16x8*>(x + (size_t)(m0 + lo) * 256 + ks * 32 + hi * 8);
    #pragma unroll
    for (int nt = 0; nt < 4; ++nt) {
      const int d = nt * 16 + lo;
      const __bf16* wrow = (nt < 2) ? (wq + d * 256) : (wk + (d - 32) * 256);
      const bf16x8 bfr = *reinterpret_cast<const bf16x8*>(wrow + ks * 32 + hi * 8);
      acc[nt] = mfma16(a, bfr, acc[nt]);
    }
  }
  #pragma unroll
  for (int nt = 0; nt < 4; ++nt) {
    const int d = nt * 16 + lo;
    const float bias = (nt < 2) ? bq[d] : bk[d - 32];
    #pragma unroll
    for (int r = 0; r < 4; ++r) {
      const size_t row = m0 + hi * 4 + r;
      float v = acc[nt][r] + bias;
      if (nt < 2) v *= LOG2E;          // fold log2(e) into Q
      const __bf16 vh = (__bf16)v;
      const __bf16 vl = (__bf16)(v - (float)vh);
      if (nt < 2) { Qh[row * 32 + d] = vh;        Ql[row * 32 + d] = vl; }
      else        { Kh[row * 32 + (d - 32)] = vh; Kl[row * 32 + (d - 32)] = vl; }
    }
  }
}

// ---------------- V projection, output TRANSPOSED: VT[b][c][l] ----------------
// operand-swapped MFMA so each lane holds 4 consecutive l -> b64 stores
__global__ __launch_bounds__(256) void v_proj(
    const __bf16* __restrict__ x, const __bf16* __restrict__ wv, const float* __restrict__ bv,
    __bf16* __restrict__ VT)
{
  const int w = threadIdx.x >> 6, lane = threadIdx.x & 63;
  const int lo = lane & 15, hi = lane >> 4;
  const int bn = blockIdx.x & 511, bc = blockIdx.x >> 9;
  const int n0 = bn * 64;
  const int c0 = bc * 64 + w * 16;
  f32x4 acc[4] = {};
  for (int ks = 0; ks < 8; ++ks) {
    const bf16x8 a = *reinterpret_cast<const bf16x8*>(wv + (size_t)(c0 + lo) * 256 + ks * 32 + hi * 8);
    #pragma unroll
    for (int nt = 0; nt < 4; ++nt) {
      const bf16x8 bfr = *reinterpret_cast<const bf16x8*>(x + (size_t)(n0 + nt * 16 + lo) * 256 + ks * 32 + hi * 8);
      acc[nt] = mfma16(bfr, a, acc[nt]);   // A=x rows(n), B=wv cols(c)
    }
  }
  const int bb = n0 >> 12;
  const int c = c0 + lo;                    // D col = c-local = lo
  const float bias = bv[c];
  #pragma unroll
  for (int nt = 0; nt < 4; ++nt) {
    const int n = (n0 + nt * 16 + hi * 4) & 4095;   // D rows = n-local = hi*4+r
    bf16x4 pk = { (__bf16)(acc[nt][0] + bias), (__bf16)(acc[nt][1] + bias),
                  (__bf16)(acc[nt][2] + bias), (__bf16)(acc[nt][3] + bias) };
    *reinterpret_cast<bf16x4*>(VT + (size_t)(bb * 256 + c) * 4096 + n) = pk;
  }
}

// ---------------- fused flash attention + reshape + residual ----------------
// TQ=32 q per block, 4 waves k-split: wave w owns j-slice [jb+16w, +16).
// NO barriers in the loop: softmax lane-local (swapped QK^T), P transposed
// through a private per-wave LDS buffer, V B-frags DIRECT from global (L2-
// resident per XCD), K register-dbuf. PV uses 32x32x16 MFMA. Epilogue: ring
// reduce-scatter of the 4 k-partials through LDS; wave w finalizes c-chunk w.
__global__ __launch_bounds__(256, 2) void attn_kernel(
    const __bf16* __restrict__ Qhi, const __bf16* __restrict__ Qlo,
    const __bf16* __restrict__ Khi, const __bf16* __restrict__ Klo,
    const __bf16* __restrict__ VT,
    const float* __restrict__ feats, const float* __restrict__ gptr,
    float* __restrict__ out)
{
  __shared__ alignas(16) __bf16 pt[4][32 * 24];    // P^T, stride 48B, 1.5KB/wave
  __shared__ alignas(16) float  ored[4][2048];     // 4 x 8KB reduce regions
  __shared__ float lred[4][32];
  __shared__ float lsumbuf[32];

  const int tid  = threadIdx.x;
  const int w    = tid >> 6, lane = tid & 63;
  const int lo   = lane & 15, hi = lane >> 4;
  const int l31  = lane & 31, h  = lane >> 5;
  const int b    = blockIdx.x & 7;                 // batch -> XCD affinity
  const int qb   = blockIdx.x >> 3;                // q-block (32 rows)

  // Q B-frags (col=q=lo, k=hi*8+e), 2 q-tiles
  bf16x8 qh[2], ql[2];
  #pragma unroll
  for (int qt = 0; qt < 2; ++qt) {
    const int qi = (b * 4096 + qb * 32 + qt * 16 + lo) * 32 + hi * 8;
    qh[qt] = *reinterpret_cast<const bf16x8*>(Qhi + qi);
    ql[qt] = *reinterpret_cast<const bf16x8*>(Qlo + qi);
  }

  // K A-frag index (row j = jb + 16w + lo, k = hi*8+e)
  const int kidx = (b * 4096 + w * 16 + lo) * 32 + hi * 8;
  // V B-frag offsets (col c = ct*32 + l31, k-slice j = jb + 16w + h*8+e)
  int voff[8];
  #pragma unroll
  for (int ct = 0; ct < 8; ++ct)
    voff[ct] = (b * 256 + ct * 32 + l31) * 4096 + w * 16 + h * 8;

  char* const ptw = (char*)&pt[w][0];

  f32x16 o[8] = {};
  f32x4  lacc4[2] = {};

  bf16x8 kh = *reinterpret_cast<const bf16x8*>(Khi + kidx);
  bf16x8 kl = *reinterpret_cast<const bf16x8*>(Klo + kidx);

  for (int t = 0; t < 64; ++t) {
    const int jb = t * 64;
    const int jn = (jb + 64) & 4095;

    // V(t) fragments direct from global (L2); independent, issued first
    bf16x8 vf[8];
    #pragma unroll
    for (int ct = 0; ct < 8; ++ct)
      vf[ct] = *reinterpret_cast<const bf16x8*>(VT + voff[ct] + jb);

    // K(t+1) register prefetch
    const bf16x8 kh2 = *reinterpret_cast<const bf16x8*>(Khi + kidx + jn * 32);
    const bf16x8 kl2 = *reinterpret_cast<const bf16x8*>(Klo + kidx + jn * 32);

    // S^T[16j][32q] = K·Q (split-bf16; Q pre-scaled by log2e)
    f32x4 s[2];
    #pragma unroll
    for (int qt = 0; qt < 2; ++qt) {
      f32x4 a = {0.f, 0.f, 0.f, 0.f};
      a = mfma16(kh, qh[qt], a);
      a = mfma16(kl, qh[qt], a);
      a = mfma16(kh, ql[qt], a);
      s[qt] = a;
    }

    // fixed-base softmax: lane owns q = qt*16+lo, j = hi*4+r
    #pragma unroll
    for (int qt = 0; qt < 2; ++qt) {
      f32x4 p4;
      #pragma unroll
      for (int r = 0; r < 4; ++r) p4[r] = __builtin_amdgcn_exp2f(s[qt][r]);
      lacc4[qt] += p4;
      bf16x4 pk = { (__bf16)p4[0], (__bf16)p4[1], (__bf16)p4[2], (__bf16)p4[3] };
      // P^T[q][j]: row q stride 48B, j bytes hi*8..hi*8+7
      *reinterpret_cast<bf16x4*>(ptw + (qt * 16 + lo) * 48 + hi * 8) = pk;
    }

    // P A-frag (private LDS, same wave -> compiler inserts lgkmcnt)
    const bf16x8 pa = *reinterpret_cast<const bf16x8*>(ptw + l31 * 48 + h * 16);

    // PV: O[32q][256c] += P[32q x 16j] · V[16j x 32c] per c-tile
    __builtin_amdgcn_s_setprio(1);
    #pragma unroll
    for (int ct = 0; ct < 8; ++ct)
      o[ct] = mfma32(pa, vf[ct], o[ct]);
    __builtin_amdgcn_s_setprio(0);

    kh = kh2; kl = kl2;
  }

  // ---- l: lane-local -> cross-hi -> cross-wave via LDS ----
  float la0 = lacc4[0][0] + lacc4[0][1] + lacc4[0][2] + lacc4[0][3];
  float la1 = lacc4[1][0] + lacc4[1][1] + lacc4[1][2] + lacc4[1][3];
  la0 += __shfl_xor(la0, 16); la0 += __shfl_xor(la0, 32);
  la1 += __shfl_xor(la1, 16); la1 += __shfl_xor(la1, 32);
  if (lane < 16) { lred[w][lane] = la0; lred[w][16 + lane] = la1; }
  __syncthreads();
  if (w == 0 && lane < 32)
    lsumbuf[lane] = lred[0][lane] + lred[1][lane] + lred[2][lane] + lred[3][lane];
  __syncthreads();

  const float g = gptr[0];
  f32x4 inv4[4];
  #pragma unroll
  for (int k = 0; k < 4; ++k) {
    const f32x4 lv = *reinterpret_cast<const f32x4*>(&lsumbuf[8 * k + 4 * h]);
    inv4[k][0] = g / lv[0]; inv4[k][1] = g / lv[1];
    inv4[k][2] = g / lv[2]; inv4[k][3] = g / lv[3];
  }

  // ---- ring reduce-scatter of O partials: wave w ends with c-chunk w ----
  // region layout [64 cl][32 q] f32, 16B-granule XOR swizzle
  #define OADDR(REG, CL, K) ((char*)&ored[REG][0] + (CL) * 128 + ((((2*(K)+h) ^ ((CL) & 7))) << 4))
  #define SEND(M)                                                              \
    { _Pragma("unroll") for (int ti = 0; ti < 2; ++ti) {                       \
        const int cl = ti * 32 + l31;                                          \
        _Pragma("unroll") for (int k = 0; k < 4; ++k) {                        \
          f32x4 v = { o[2*(M)+ti][4*k], o[2*(M)+ti][4*k+1],                    \
                      o[2*(M)+ti][4*k+2], o[2*(M)+ti][4*k+3] };                \
          *reinterpret_cast<f32x4*>(OADDR(w, cl, k)) = v; } } }
  #define RECV(M, SRC)                                                         \
    { _Pragma("unroll") for (int ti = 0; ti < 2; ++ti) {                       \
        const int cl = ti * 32 + l31;                                          \
        _Pragma("unroll") for (int k = 0; k < 4; ++k) {                        \
          const f32x4 v = *reinterpret_cast<const f32x4*>(OADDR(SRC, cl, k));  \
          o[2*(M)+ti][4*k]   += v[0]; o[2*(M)+ti][4*k+1] += v[1];              \
          o[2*(M)+ti][4*k+2] += v[2]; o[2*(M)+ti][4*k+3] += v[3]; } } }

  #pragma unroll
  for (int r = 1; r < 4; ++r) {
    const int m = (w + r) & 3;
    if      (m == 0) SEND(0)
    else if (m == 1) SEND(1)
    else if (m == 2) SEND(2)
    else             SEND(3)
    __syncthreads();
    const int src = (w - r) & 3;
    if      (w == 0) RECV(0, src)
    else if (w == 1) RECV(1, src)
    else if (w == 2) RECV(2, src)
    else             RECV(3, src)
    __syncthreads();
  }
  #undef OADDR
  #undef SEND
  #undef RECV

  // ---- epilogue: wave w writes c-chunk w: y = gamma*O/l + x ----
  const int obase = b * (256 * 4096);
  const int q0 = qb * 32 + 4 * h;
  #define EPI(M)                                                               \
    { _Pragma("unroll") for (int ti = 0; ti < 2; ++ti) {                       \
        const int c = (2*(M)+ti) * 32 + l31;                                   \
        _Pragma("unroll") for (int k = 0; k < 4; ++k) {                        \
          const int idx = obase + c * 4096 + q0 + 8 * k;                       \
          const float4 xr = *reinterpret_cast<const float4*>(feats + idx);     \
          float4 y;                                                            \
          y.x = o[2*(M)+ti][4*k]   * inv4[k][0] + xr.x;                        \
          y.y = o[2*(M)+ti][4*k+1] * inv4[k][1] + xr.y;                        \
          y.z = o[2*(M)+ti][4*k+2] * inv4[k][2] + xr.z;                        \
          y.w = o[2*(M)+ti][4*k+3] * inv4[k][3] + xr.w;                        \
          *reinterpret_cast<float4*>(out + idx) = y; } } }
  if      (w == 0) EPI(0)
  else if (w == 1) EPI(1)
  else if (w == 2) EPI(2)
  else             EPI(3)
  #undef EPI
}

extern "C" void kernel_launch(void* const* d_in, const int* in_sizes, int n_in,
                              void* d_out, int out_size, void* d_ws, size_t ws_size,
                              hipStream_t stream) {
  const float* feats = (const float*)d_in[0];
  const float* Wq    = (const float*)d_in[1];
  const float* bq    = (const float*)d_in[2];
  const float* Wk    = (const float*)d_in[3];
  const float* bk    = (const float*)d_in[4];
  const float* Wv    = (const float*)d_in[5];
  const float* bv    = (const float*)d_in[6];
  const float* gamma = (const float*)d_in[7];
  float* out = (float*)d_out;

  // workspace layout (bytes)
  char* ws = (char*)d_ws;
  const size_t SZ_X  = 16777216;           // x bf16 [32768][256]
  const size_t SZ_QK = 2097152;            // each of Qh/Ql/Kh/Kl [32768][32]
  const size_t SZ_VT = 16777216;           // VT bf16 [8][256][4096]
  const size_t NEED = SZ_X + 4 * SZ_QK + SZ_VT + 2 * 16384 + 131072;
  if (ws_size < NEED) return;

  __bf16* xb  = (__bf16*)(ws);
  __bf16* Qh  = (__bf16*)(ws + SZ_X);
  __bf16* Ql  = (__bf16*)(ws + SZ_X + SZ_QK);
  __bf16* Kh  = (__bf16*)(ws + SZ_X + 2 * SZ_QK);
  __bf16* Kl  = (__bf16*)(ws + SZ_X + 3 * SZ_QK);
  __bf16* VT  = (__bf16*)(ws + SZ_X + 4 * SZ_QK);
  __bf16* wqb = (__bf16*)(ws + SZ_X + 4 * SZ_QK + SZ_VT);
  __bf16* wkb = wqb + 32 * 256;
  __bf16* wvb = wkb + 32 * 256;

  cvt_f32_to_bf16<<<2048, 256, 0, stream>>>(feats, xb, 8388608 / 4);
  cvt_weights<<<80, 256, 0, stream>>>(Wq, Wk, Wv, wqb, wkb, wvb);

  qk_proj<<<512, 256, 0, stream>>>(xb, wqb, wkb, bq, bk, Qh, Ql, Kh, Kl);
  v_proj <<<2048, 256, 0, stream>>>(xb, wvb, bv, VT);
  attn_kernel<<<1024, 256, 0, stream>>>(Qh, Ql, Kh, Kl, VT, feats, gamma, out);
}

// Round 8
// 212.536 us; speedup vs baseline: 1.6025x; 1.6025x over previous
//
#include <hip/hip_runtime.h>

#define LOG2E 1.44269504088896340736f

typedef __attribute__((ext_vector_type(4)))  float  f32x4;
typedef __attribute__((ext_vector_type(16))) float  f32x16;
typedef __attribute__((ext_vector_type(8)))  __bf16 bf16x8;
typedef __attribute__((ext_vector_type(4)))  __bf16 bf16x4;

static __device__ __forceinline__ f32x4 mfma16(bf16x8 a, bf16x8 b, f32x4 c) {
  return __builtin_amdgcn_mfma_f32_16x16x32_bf16(a, b, c, 0, 0, 0);
}
static __device__ __forceinline__ f32x16 mfma32(bf16x8 a, bf16x8 b, f32x16 c) {
  return __builtin_amdgcn_mfma_f32_32x32x16_bf16(a, b, c, 0, 0, 0);
}

// B=8, L=4096, C=256, C8=32 hardcoded.

// ---------------- fp32 -> bf16 conversion (vectorized) ----------------
__global__ void cvt_f32_to_bf16(const float* __restrict__ s, __bf16* __restrict__ d, int n4) {
  const int stride = gridDim.x * blockDim.x;
  for (int i = blockIdx.x * blockDim.x + threadIdx.x; i < n4; i += stride) {
    const float4 v = reinterpret_cast<const float4*>(s)[i];
    bf16x4 o = { (__bf16)v.x, (__bf16)v.y, (__bf16)v.z, (__bf16)v.w };
    reinterpret_cast<bf16x4*>(d)[i] = o;
  }
}

// all three weight matrices in one launch
__global__ __launch_bounds__(256) void cvt_weights(
    const float* __restrict__ wq, const float* __restrict__ wk, const float* __restrict__ wv,
    __bf16* __restrict__ dq, __bf16* __restrict__ dk, __bf16* __restrict__ dv) {
  const int i = blockIdx.x * 256 + threadIdx.x;
  const float* s; __bf16* d; int off;
  if (i < 2048)      { s = wq; d = dq; off = i; }
  else if (i < 4096) { s = wk; d = dk; off = i - 2048; }
  else               { s = wv; d = dv; off = i - 4096; }
  const float4 v = reinterpret_cast<const float4*>(s)[off];
  bf16x4 o = { (__bf16)v.x, (__bf16)v.y, (__bf16)v.z, (__bf16)v.w };
  reinterpret_cast<bf16x4*>(d)[off] = o;
}

// ---------------- Q/K projection: split-bf16 out, Q pre-scaled by LOG2E ----------------
__global__ __launch_bounds__(256) void qk_proj(
    const __bf16* __restrict__ x, const __bf16* __restrict__ wq, const __bf16* __restrict__ wk,
    const float* __restrict__ bq, const float* __restrict__ bk,
    __bf16* __restrict__ Qh, __bf16* __restrict__ Ql,
    __bf16* __restrict__ Kh, __bf16* __restrict__ Kl)
{
  const int w = threadIdx.x >> 6, lane = threadIdx.x & 63;
  const int lo = lane & 15, hi = lane >> 4;
  const int m0 = blockIdx.x * 64 + w * 16;
  f32x4 acc[4] = {};
  for (int ks = 0; ks < 8; ++ks) {
    const bf16x8 a = *reinterpret_cast<const bf16x8*>(x + (size_t)(m0 + lo) * 256 + ks * 32 + hi * 8);
    #pragma unroll
    for (int nt = 0; nt < 4; ++nt) {
      const int d = nt * 16 + lo;
      const __bf16* wrow = (nt < 2) ? (wq + d * 256) : (wk + (d - 32) * 256);
      const bf16x8 bfr = *reinterpret_cast<const bf16x8*>(wrow + ks * 32 + hi * 8);
      acc[nt] = mfma16(a, bfr, acc[nt]);
    }
  }
  #pragma unroll
  for (int nt = 0; nt < 4; ++nt) {
    const int d = nt * 16 + lo;
    const float bias = (nt < 2) ? bq[d] : bk[d - 32];
    #pragma unroll
    for (int r = 0; r < 4; ++r) {
      const size_t row = m0 + hi * 4 + r;
      float v = acc[nt][r] + bias;
      if (nt < 2) v *= LOG2E;          // fold log2(e) into Q
      const __bf16 vh = (__bf16)v;
      const __bf16 vl = (__bf16)(v - (float)vh);
      if (nt < 2) { Qh[row * 32 + d] = vh;        Ql[row * 32 + d] = vl; }
      else        { Kh[row * 32 + (d - 32)] = vh; Kl[row * 32 + (d - 32)] = vl; }
    }
  }
}

// ---------------- V projection, output TRANSPOSED: VT[b][c][l] ----------------
__global__ __launch_bounds__(256) void v_proj(
    const __bf16* __restrict__ x, const __bf16* __restrict__ wv, const float* __restrict__ bv,
    __bf16* __restrict__ VT)
{
  const int w = threadIdx.x >> 6, lane = threadIdx.x & 63;
  const int lo = lane & 15, hi = lane >> 4;
  const int bn = blockIdx.x & 511, bc = blockIdx.x >> 9;
  const int n0 = bn * 64;
  const int c0 = bc * 64 + w * 16;
  f32x4 acc[4] = {};
  for (int ks = 0; ks < 8; ++ks) {
    const bf16x8 a = *reinterpret_cast<const bf16x8*>(wv + (size_t)(c0 + lo) * 256 + ks * 32 + hi * 8);
    #pragma unroll
    for (int nt = 0; nt < 4; ++nt) {
      const bf16x8 bfr = *reinterpret_cast<const bf16x8*>(x + (size_t)(n0 + nt * 16 + lo) * 256 + ks * 32 + hi * 8);
      acc[nt] = mfma16(bfr, a, acc[nt]);   // A=x rows(n), B=wv cols(c)
    }
  }
  const int bb = n0 >> 12;
  const int c = c0 + lo;
  const float bias = bv[c];
  #pragma unroll
  for (int nt = 0; nt < 4; ++nt) {
    const int n = (n0 + nt * 16 + hi * 4) & 4095;
    bf16x4 pk = { (__bf16)(acc[nt][0] + bias), (__bf16)(acc[nt][1] + bias),
                  (__bf16)(acc[nt][2] + bias), (__bf16)(acc[nt][3] + bias) };
    *reinterpret_cast<bf16x4*>(VT + (size_t)(bb * 256 + c) * 4096 + n) = pk;
  }
}

// ---------------- fused flash attention + reshape + residual ----------------
// TQ=64, 4 waves in a 2x2 (q-group x c-group) split: wave owns 32q x 128c.
// Swapped QK^T -> lane-local softmax (zero shuffles); QK computed x2 (once per
// q-group pair) -- buys zero cross-wave P traffic. P lives in a PRIVATE 4KB
// per-wave LDS buffer (no barrier). PV uses 32x32x16 MFMA: each 16B V read
// feeds a full 32q-row MFMA. V tile [256c][64j] staged coalesced by
// global_load_lds (pre-swizzled source, linear dest), double-buffered; ONE raw
// s_barrier/iter with vmcnt(8) (K prefetch stays in flight). Swizzle
// slot ^ ((row ^ row>>3)&7) makes 32-row b128 reads conflict-free.
__global__ __launch_bounds__(256, 2) void attn_kernel(
    const __bf16* __restrict__ Qhi, const __bf16* __restrict__ Qlo,
    const __bf16* __restrict__ Khi, const __bf16* __restrict__ Klo,
    const __bf16* __restrict__ VT,
    const float* __restrict__ feats, const float* __restrict__ gptr,
    float* __restrict__ out)
{
  __shared__ alignas(16) __bf16 vlds[2][16384];  // [256c][64j] swizzled, 2x32KB
  __shared__ alignas(16) __bf16 pbuf[4][2048];   // per-wave P [32q][64j], 4KB

  const int tid  = threadIdx.x;
  const int w    = tid >> 6, lane = tid & 63;
  const int lo   = lane & 15, hi = lane >> 4;
  const int l31  = lane & 31, h  = lane >> 5;
  const int qg   = w & 1,    cg  = w >> 1;
  const int b    = blockIdx.x & 7;               // batch -> XCD affinity
  const int qblk = (blockIdx.x >> 3) * 64;
  const int qw   = qblk + qg * 32;               // wave's 32 q rows

  // Q B-frags (col=q=lo, k=hi*8+e), 2 q-tiles of the wave's 32 q
  bf16x8 qh[2], ql[2];
  #pragma unroll
  for (int qt = 0; qt < 2; ++qt) {
    const int qi = (b * 4096 + qw + qt * 16 + lo) * 32 + hi * 8;
    qh[qt] = *reinterpret_cast<const bf16x8*>(Qhi + qi);
    ql[qt] = *reinterpret_cast<const bf16x8*>(Qlo + qi);
  }

  // K A-frag base (row j = jb + jt*16 + lo, k = hi*8+e)
  const int kbase = (b * 4096 + lo) * 32 + hi * 8;

  // V stage source (rule 21: linear LDS dest, pre-swizzled global source)
  const int cc   = tid >> 3;                      // base row (+ g*32)
  const int scc  = (tid & 7) ^ ((cc ^ (cc >> 3)) & 7);
  const __bf16* const vsrc = VT + (size_t)(b * 256 + cc) * 4096;

  // V read: row = cg*128 + ct*32 + l31
  int vrow[4], vsw[4];
  #pragma unroll
  for (int ct = 0; ct < 4; ++ct) {
    const int row = cg * 128 + ct * 32 + l31;
    vrow[ct] = row * 128;
    vsw[ct]  = (row ^ (row >> 3)) & 7;
  }
  // P swizzles
  int swzq[2];
  #pragma unroll
  for (int qt = 0; qt < 2; ++qt) {
    const int q = qt * 16 + lo;
    swzq[qt] = (q ^ (q >> 3)) & 7;
  }
  const int swzp = (l31 ^ (l31 >> 3)) & 7;
  char* const pwb = (char*)&pbuf[w][0];

  f32x16 o[4] = {};
  f32x4  lacc[2] = {};

  #define STAGE_V(JB, BUF)                                                      \
    {                                                                           \
      _Pragma("unroll")                                                         \
      for (int g = 0; g < 8; ++g) {                                             \
        const int slot = scc ^ ((g & 1) << 2);                                  \
        __builtin_amdgcn_global_load_lds(                                       \
            (const __attribute__((address_space(1))) void*)(vsrc + (size_t)g * 32 * 4096 + (JB) + slot * 8), \
            (__attribute__((address_space(3))) void*)(&vlds[BUF][g * 2048 + tid * 8]), \
            16, 0, 0);                                                          \
      }                                                                         \
    }

  // ---- prologue: stage V(0), load K(0), drain, barrier ----
  STAGE_V(0, 0);
  bf16x8 kh[4], kl[4];
  #pragma unroll
  for (int jt = 0; jt < 4; ++jt) {
    kh[jt] = *reinterpret_cast<const bf16x8*>(Khi + kbase + (jt * 16) * 32);
    kl[jt] = *reinterpret_cast<const bf16x8*>(Klo + kbase + (jt * 16) * 32);
  }
  asm volatile("s_waitcnt vmcnt(0)" ::: "memory");
  __builtin_amdgcn_s_barrier();

  #pragma unroll 2
  for (int t = 0; t < 64; ++t) {
    const int jb  = t * 64;
    const int jn  = (jb + 64) & 4095;
    const int cur = t & 1, nxt = cur ^ 1;

    // 1. S^T = K·Q + lane-local softmax + private P write (per jt-pair)
    #pragma unroll
    for (int jp = 0; jp < 2; ++jp) {
      f32x4 s[2][2];
      #pragma unroll
      for (int jj = 0; jj < 2; ++jj) {
        const int jt = jp * 2 + jj;
        #pragma unroll
        for (int qt = 0; qt < 2; ++qt) {
          f32x4 a = {0.f, 0.f, 0.f, 0.f};
          a = mfma16(kh[jt], qh[qt], a);
          a = mfma16(kl[jt], qh[qt], a);
          a = mfma16(kh[jt], ql[qt], a);
          s[jj][qt] = a;
        }
      }
      #pragma unroll
      for (int jj = 0; jj < 2; ++jj) {
        const int jt = jp * 2 + jj;
        #pragma unroll
        for (int qt = 0; qt < 2; ++qt) {
          f32x4 p4;
          #pragma unroll
          for (int r = 0; r < 4; ++r) p4[r] = __builtin_amdgcn_exp2f(s[jj][qt][r]);
          lacc[qt] += p4;
          bf16x4 pk = { (__bf16)p4[0], (__bf16)p4[1], (__bf16)p4[2], (__bf16)p4[3] };
          const int q = qt * 16 + lo;
          *reinterpret_cast<bf16x4*>(pwb + q * 128 +
              (((jt * 2 + (hi >> 1)) ^ swzq[qt]) << 4) + ((hi & 1) << 3)) = pk;
        }
      }
    }

    // 2. stage V(t+1) (oldest vmem this iter -> drained by vmcnt(8) at barrier)
    STAGE_V(jn, nxt);
    asm volatile("" ::: "memory");
    __builtin_amdgcn_sched_barrier(0);

    // 3. K(t+1) register prefetch (stays in flight across the barrier)
    bf16x8 kh2[4], kl2[4];
    #pragma unroll
    for (int jt = 0; jt < 4; ++jt) {
      kh2[jt] = *reinterpret_cast<const bf16x8*>(Khi + kbase + (jn + jt * 16) * 32);
      kl2[jt] = *reinterpret_cast<const bf16x8*>(Klo + kbase + (jn + jt * 16) * 32);
    }

    // 4. P A-frags (private LDS, same wave; compiler inserts lgkmcnt)
    bf16x8 pa[4];
    #pragma unroll
    for (int ks = 0; ks < 4; ++ks)
      pa[ks] = *reinterpret_cast<const bf16x8*>(pwb + l31 * 128 + (((ks * 2 + h) ^ swzp) << 4));

    // 5. PV: O[32q x 128c] += P·V with 32x32x16 MFMA (V from shared LDS tile)
    const char* const vb = (const char*)&vlds[cur][0];
    __builtin_amdgcn_s_setprio(1);
    #pragma unroll
    for (int ct = 0; ct < 4; ++ct) {
      #pragma unroll
      for (int ks = 0; ks < 4; ++ks) {
        const bf16x8 vf = *reinterpret_cast<const bf16x8*>(
            vb + vrow[ct] + (((ks * 2 + h) ^ vsw[ct]) << 4));
        o[ct] = mfma32(pa[ks], vf, o[ct]);
      }
    }
    __builtin_amdgcn_s_setprio(0);

    // 6. barrier: stage(t+1) retired, K(t+1) in flight, LDS reads done
    asm volatile("s_waitcnt vmcnt(8) lgkmcnt(0)" ::: "memory");
    __builtin_amdgcn_sched_barrier(0);
    __builtin_amdgcn_s_barrier();
    asm volatile("" ::: "memory");
    __builtin_amdgcn_sched_barrier(0);

    // 7. rotate K registers
    #pragma unroll
    for (int jt = 0; jt < 4; ++jt) { kh[jt] = kh2[jt]; kl[jt] = kl2[jt]; }
  }
  #undef STAGE_V

  // ---- l: each wave's l is complete for its 32q (full j coverage) ----
  float la0 = lacc[0][0] + lacc[0][1] + lacc[0][2] + lacc[0][3];
  float la1 = lacc[1][0] + lacc[1][1] + lacc[1][2] + lacc[1][3];
  la0 += __shfl_xor(la0, 16); la0 += __shfl_xor(la0, 32);
  la1 += __shfl_xor(la1, 16); la1 += __shfl_xor(la1, 32);
  asm volatile("s_waitcnt lgkmcnt(0)" ::: "memory");   // P buffer reads done
  float* const lredw = (float*)&pbuf[w][0];            // reuse private P space
  if (lane < 16) { lredw[lane] = la0; lredw[16 + lane] = la1; }

  const float g = gptr[0];
  f32x4 inv[4];
  #pragma unroll
  for (int a = 0; a < 4; ++a) {
    const f32x4 lv = *reinterpret_cast<const f32x4*>(&lredw[8 * a + 4 * h]);
    inv[a][0] = g / lv[0]; inv[a][1] = g / lv[1];
    inv[a][2] = g / lv[2]; inv[a][3] = g / lv[3];
  }

  // ---- epilogue: y[b, c*4096+q] = gamma*O[q][c]/l + x ----
  const int obase = b * (256 * 4096);
  const int q0 = qblk + qg * 32 + 4 * h;
  #pragma unroll
  for (int ct = 0; ct < 4; ++ct) {
    const int c = cg * 128 + ct * 32 + l31;
    #pragma unroll
    for (int a = 0; a < 4; ++a) {
      const int idx = obase + c * 4096 + q0 + 8 * a;
      const float4 xr = *reinterpret_cast<const float4*>(feats + idx);
      float4 y;
      y.x = o[ct][4 * a]     * inv[a][0] + xr.x;
      y.y = o[ct][4 * a + 1] * inv[a][1] + xr.y;
      y.z = o[ct][4 * a + 2] * inv[a][2] + xr.z;
      y.w = o[ct][4 * a + 3] * inv[a][3] + xr.w;
      *reinterpret_cast<float4*>(out + idx) = y;
    }
  }
}

extern "C" void kernel_launch(void* const* d_in, const int* in_sizes, int n_in,
                              void* d_out, int out_size, void* d_ws, size_t ws_size,
                              hipStream_t stream) {
  const float* feats = (const float*)d_in[0];
  const float* Wq    = (const float*)d_in[1];
  const float* bq    = (const float*)d_in[2];
  const float* Wk    = (const float*)d_in[3];
  const float* bk    = (const float*)d_in[4];
  const float* Wv    = (const float*)d_in[5];
  const float* bv    = (const float*)d_in[6];
  const float* gamma = (const float*)d_in[7];
  float* out = (float*)d_out;

  // workspace layout (bytes)
  char* ws = (char*)d_ws;
  const size_t SZ_X  = 16777216;           // x bf16 [32768][256]
  const size_t SZ_QK = 2097152;            // each of Qh/Ql/Kh/Kl [32768][32]
  const size_t SZ_VT = 16777216;           // VT bf16 [8][256][4096]
  const size_t NEED = SZ_X + 4 * SZ_QK + SZ_VT + 2 * 16384 + 131072;
  if (ws_size < NEED) return;

  __bf16* xb  = (__bf16*)(ws);
  __bf16* Qh  = (__bf16*)(ws + SZ_X);
  __bf16* Ql  = (__bf16*)(ws + SZ_X + SZ_QK);
  __bf16* Kh  = (__bf16*)(ws + SZ_X + 2 * SZ_QK);
  __bf16* Kl  = (__bf16*)(ws + SZ_X + 3 * SZ_QK);
  __bf16* VT  = (__bf16*)(ws + SZ_X + 4 * SZ_QK);
  __bf16* wqb = (__bf16*)(ws + SZ_X + 4 * SZ_QK + SZ_VT);
  __bf16* wkb = wqb + 32 * 256;
  __bf16* wvb = wkb + 32 * 256;

  cvt_f32_to_bf16<<<2048, 256, 0, stream>>>(feats, xb, 8388608 / 4);
  cvt_weights<<<80, 256, 0, stream>>>(Wq, Wk, Wv, wqb, wkb, wvb);

  qk_proj<<<512, 256, 0, stream>>>(xb, wqb, wkb, bq, bk, Qh, Ql, Kh, Kl);
  v_proj <<<2048, 256, 0, stream>>>(xb, wvb, bv, VT);
  attn_kernel<<<512, 256, 0, stream>>>(Qh, Ql, Kh, Kl, VT, feats, gamma, out);
}